// Round 6
// baseline (191.625 us; speedup 1.0000x reference)
//
#include <hip/hip_runtime.h>
#include <hip/hip_bf16.h>
#include <math.h>

#define TPB 512
// LDS: one uint4 (8 x bf16) per (element, channel) row; row stride 17 u4 (k=1 odd -> conflict-min)
// uX  region: u4 [0    .. 1088)  x -> attended
// uXR region: u4 [1088 .. 2176)  xr -> h
// epilogue: whole union viewed as f32 [64][136]  (2176 u4 = 8704 f32 = 64*136 exactly)
#define SMEM_BYTES 34816

// ---- Cl(3,0): slot s (0..43) of the GP pair-sum (verified rounds 4-5) ----
constexpr int SCNT[44] = {1,1,1,1,1,1,1,1, 3,1,1,1, 2,2,2,2,2,2, 1,1,1, 3,
                          3, 2,2,2, 1,1,1,1,1,1, 2,2,2, 3, 1,1,1,1,1,1,1,1};
constexpr int T1I[44] = {0,0,0,0,0,0,0,0, 1,1,2,3, 2,1,1,1,1,2, 3,2,1, 1,
                         4, 4,4,5, 6,5,4,4,5,6, 5,4,4, 4, 7,7,7,7,7,7,7,7};
constexpr int T1K[44] = {0,1,2,3,4,5,6,7, 1,0,0,0, 4,4,5,2,3,3, 7,7,7, 6,
                         4, 2,1,1, 7,7,7,0,0,0, 6,6,5, 3, 7,6,5,4,3,2,1,0};
constexpr int T1S[44] = {1,1,1,1,1,1,1,1, 1,1,1,1, 0,1,1,1,1,1, 1,0,1, 1,
                         0, 1,0,0, 0,1,0,1,1,1, 0,1,0, 1, 0,0,1,0,1,0,1,1};
constexpr int T2I[44] = {0,0,0,0,0,0,0,0, 2,0,0,0, 3,3,2,2,3,3, 0,0,0, 2,
                         5, 5,6,6, 0,0,0,0,0,0, 6,6,5, 5, 0,0,0,0,0,0,0,0};
constexpr int T2K[44] = {0,0,0,0,0,0,0,0, 2,0,0,0, 5,6,6,1,1,2, 0,0,0, 5,
                         5, 3,3,2, 0,0,0,0,0,0, 5,4,4, 2, 0,0,0,0,0,0,0,0};
constexpr int T2S[44] = {1,1,1,1,1,1,1,1, 1,1,1,1, 0,0,1,0,0,0, 1,1,1, 0,
                         0, 1,1,0, 1,1,1,1,1,1, 1,0,1, 0, 1,1,1,1,1,1,1,1};
constexpr int T3I[44] = {0,0,0,0,0,0,0,0, 3,0,0,0, 0,0,0,0,0,0, 0,0,0, 3,
                         6, 0,0,0, 0,0,0,0,0,0, 0,0,0, 6, 0,0,0,0,0,0,0,0};
constexpr int T3K[44] = {0,0,0,0,0,0,0,0, 3,0,0,0, 0,0,0,0,0,0, 0,0,0, 4,
                         6, 0,0,0, 0,0,0,0,0,0, 0,0,0, 1, 0,0,0,0,0,0,0,0};
constexpr int T3S[44] = {1,1,1,1,1,1,1,1, 1,1,1,1, 1,1,1,1,1,1, 1,1,1, 1,
                         0, 1,1,1, 1,1,1,1,1,1, 1,1,1, 1, 1,1,1,1,1,1,1,1};
constexpr int CP[44] = {
    0, 1,1,1, 2,2,2, 3,
    4, 5,5,5, 6,6,6, 7,7,7, 8,8,8, 9,
    10, 11,11,11, 12,12,12, 13,13,13, 14,14,14, 15,
    16, 17,17,17, 18,18,18, 19};
constexpr int CJ[44] = {
    0, 1,2,3, 4,5,6, 7,
    0, 1,2,3, 1,2,3, 4,5,6, 4,5,6, 7,
    0, 1,2,3, 1,2,3, 4,5,6, 4,5,6, 7,
    0, 1,2,3, 4,5,6, 7};

__device__ __forceinline__ float sigmoidf_(float v) {
    return __builtin_amdgcn_rcpf(1.0f + __expf(-v));
}
__device__ __forceinline__ unsigned pk2(float lo, float hi) {
    __hip_bfloat162 h = __float22bfloat162_rn(make_float2(lo, hi));
    return *reinterpret_cast<unsigned*>(&h);
}
__device__ __forceinline__ uint4 pkrow(const float* v) {
    return make_uint4(pk2(v[0],v[1]), pk2(v[2],v[3]), pk2(v[4],v[5]), pk2(v[6],v[7]));
}
__device__ __forceinline__ void unpkrow(uint4 u, float* v) {
    v[0]=__uint_as_float(u.x<<16); v[1]=__uint_as_float(u.x&0xffff0000u);
    v[2]=__uint_as_float(u.y<<16); v[3]=__uint_as_float(u.y&0xffff0000u);
    v[4]=__uint_as_float(u.z<<16); v[5]=__uint_as_float(u.z&0xffff0000u);
    v[6]=__uint_as_float(u.w<<16); v[7]=__uint_as_float(u.w&0xffff0000u);
}

__global__ __launch_bounds__(TPB, 8)
void mv_block_kernel(const float* __restrict__ xg,
                     const float* __restrict__ w_right,
                     const float* __restrict__ a_norm,
                     const float* __restrict__ w_gp,
                     const float* __restrict__ w_left,
                     const float* __restrict__ b_left,
                     const float* __restrict__ w_up,
                     const float* __restrict__ b_up,
                     const float* __restrict__ a_act,
                     const float* __restrict__ b_act,
                     const float* __restrict__ w_down,
                     const float* __restrict__ b_down,
                     float* __restrict__ outg)
{
    extern __shared__ float sm[];
    uint4* uX  = (uint4*)sm;            // [64][17] u4 rows: x, later attended (bf16 pairs)
    uint4* uXR = uX + 1088;             // [64][17] u4 rows: xr, later h
    const int t = threadIdx.x;
    const int b = t & 63;                                   // lane = batch element
    const int w = __builtin_amdgcn_readfirstlane(t >> 6);   // wave 0..7 (uniform)
    const int mA = w, mB = w + 8;                           // two channels per wave
    const int g = blockIdx.x;

    // ---------- stage x: coalesced f32 global -> packed bf16 LDS rows ----------
    {
        const float4* xs = (const float4*)xg + (size_t)g * 2048;
        uint2* u2 = (uint2*)sm;
        #pragma unroll
        for (int r = 0; r < 4; ++r) {
            const int idx = r * TPB + t;
            const float4 v = xs[idx];
            const int el = idx >> 5, q = idx & 31;          // n = q>>1, half = q&1
            u2[(el*17 + (q>>1))*2 + (q&1)] = make_uint2(pk2(v.x,v.y), pk2(v.z,v.w));
        }
    }
    __syncthreads();

    // ---------- phase A: right-linear + left-linear (2 channels, weights in SGPRs) ----------
    float xrA[8] = {0,0,0,0,0,0,0,0}, xrB[8] = {0,0,0,0,0,0,0,0};
    float lfA[8] = {0,0,0,0,0,0,0,0}, lfB[8] = {0,0,0,0,0,0,0,0};
    {
        #pragma unroll 1
        for (int n = 0; n < 16; ++n) {
            float xa[8];
            unpkrow(uX[b*17 + n], xa);
            const float4 wa = *(const float4*)&w_right[(mA*16+n)*4];
            const float4 wb = *(const float4*)&w_right[(mB*16+n)*4];
            const float4 va = *(const float4*)&w_left [(mA*16+n)*4];
            const float4 vb = *(const float4*)&w_left [(mB*16+n)*4];
            xrA[0]+=xa[0]*wa.x; xrA[1]+=xa[1]*wa.y; xrA[2]+=xa[2]*wa.y; xrA[3]+=xa[3]*wa.y;
            xrA[4]+=xa[4]*wa.z; xrA[5]+=xa[5]*wa.z; xrA[6]+=xa[6]*wa.z; xrA[7]+=xa[7]*wa.w;
            xrB[0]+=xa[0]*wb.x; xrB[1]+=xa[1]*wb.y; xrB[2]+=xa[2]*wb.y; xrB[3]+=xa[3]*wb.y;
            xrB[4]+=xa[4]*wb.z; xrB[5]+=xa[5]*wb.z; xrB[6]+=xa[6]*wb.z; xrB[7]+=xa[7]*wb.w;
            lfA[0]+=xa[0]*va.x; lfA[1]+=xa[1]*va.y; lfA[2]+=xa[2]*va.y; lfA[3]+=xa[3]*va.y;
            lfA[4]+=xa[4]*va.z; lfA[5]+=xa[5]*va.z; lfA[6]+=xa[6]*va.z; lfA[7]+=xa[7]*va.w;
            lfB[0]+=xa[0]*vb.x; lfB[1]+=xa[1]*vb.y; lfB[2]+=xa[2]*vb.y; lfB[3]+=xa[3]*vb.y;
            lfB[4]+=xa[4]*vb.z; lfB[5]+=xa[5]*vb.z; lfB[6]+=xa[6]*vb.z; lfB[7]+=xa[7]*vb.w;
        }
    }

    // ---------- phase B: gated per-grade normalization ----------
    #pragma unroll
    for (int q = 0; q < 2; ++q) {
        float* xr = q ? xrB : xrA;
        const int m = q ? mB : mA;
        const float q0 = xr[0]*xr[0];
        const float q1 = xr[1]*xr[1] + xr[2]*xr[2] + xr[3]*xr[3];
        const float q2 = xr[4]*xr[4] + xr[5]*xr[5] + xr[6]*xr[6];
        const float q3 = xr[7]*xr[7];
        const float4 an = *(const float4*)&a_norm[m*4];
        const float i0 = __builtin_amdgcn_rcpf(sigmoidf_(an.x)*(sqrtf(q0)-1.0f)+1.0f + 1e-6f);
        const float i1 = __builtin_amdgcn_rcpf(sigmoidf_(an.y)*(sqrtf(q1)-1.0f)+1.0f + 1e-6f);
        const float i2 = __builtin_amdgcn_rcpf(sigmoidf_(an.z)*(sqrtf(q2)-1.0f)+1.0f + 1e-6f);
        const float i3 = __builtin_amdgcn_rcpf(sigmoidf_(an.w)*(sqrtf(q3)-1.0f)+1.0f + 1e-6f);
        xr[0]*=i0; xr[1]*=i1; xr[2]*=i1; xr[3]*=i1;
        xr[4]*=i2; xr[5]*=i2; xr[6]*=i2; xr[7]*=i3;
    }
    uXR[b*17 + mA] = pkrow(xrA);
    uXR[b*17 + mB] = pkrow(xrB);
    __syncthreads();

    // ---------- phase C: direct GP; pair products shared across the wave's 2 channels ----------
    float gpA[8] = {0,0,0,0,0,0,0,0}, gpB[8] = {0,0,0,0,0,0,0,0};
    {
        #pragma unroll 1
        for (int n = 0; n < 16; ++n) {
            float xv[8], rv[8];
            unpkrow(uX [b*17 + n], xv);
            unpkrow(uXR[b*17 + n], rv);
            const float* wa = &w_gp[(mA*16+n)*20];     // uniform -> SGPRs
            const float* wb = &w_gp[(mB*16+n)*20];     // uniform -> SGPRs
            #pragma unroll
            for (int s = 0; s < 44; ++s) {
                float tz = T1S[s] ? xv[T1I[s]]*rv[T1K[s]] : -(xv[T1I[s]]*rv[T1K[s]]);
                if (SCNT[s] > 1) tz = T2S[s] ? fmaf(xv[T2I[s]], rv[T2K[s]], tz)
                                             : fmaf(-xv[T2I[s]], rv[T2K[s]], tz);
                if (SCNT[s] > 2) tz = T3S[s] ? fmaf(xv[T3I[s]], rv[T3K[s]], tz)
                                             : fmaf(-xv[T3I[s]], rv[T3K[s]], tz);
                gpA[CJ[s]] = fmaf(wa[CP[s]], tz, gpA[CJ[s]]);
                gpB[CJ[s]] = fmaf(wb[CP[s]], tz, gpB[CJ[s]]);
            }
        }
    }
    __syncthreads();   // all C reads of X/XR done before att overwrites X

    // ---------- attended = (left + b_left + gp)/sqrt(2); f32 in regs, bf16 into X ----------
    float attA[8], attB[8];
    lfA[0] += b_left[mA];
    lfB[0] += b_left[mB];
    #pragma unroll
    for (int i = 0; i < 8; ++i) {
        attA[i] = (lfA[i] + gpA[i]) * 0.70710678118654752f;
        attB[i] = (lfB[i] + gpB[i]) * 0.70710678118654752f;
    }
    uX[b*17 + mA] = pkrow(attA);
    uX[b*17 + mB] = pkrow(attB);
    __syncthreads();

    // ---------- phase D: up -> silu -> down, 4 chunks of 16 m2; h bf16 in XR region ----------
    float oaccA[8] = {0,0,0,0,0,0,0,0}, oaccB[8] = {0,0,0,0,0,0,0,0};
    #pragma unroll 1
    for (int ch = 0; ch < 4; ++ch) {
        const int m2a = ch*16 + w;
        const int m2b = ch*16 + 8 + w;
        float h0[8] = {0,0,0,0,0,0,0,0}, h1[8] = {0,0,0,0,0,0,0,0};
        {
            #pragma unroll 1
            for (int n = 0; n < 16; ++n) {
                float aa[8];
                unpkrow(uX[b*17 + n], aa);
                const float4 wA = *(const float4*)&w_up[(m2a*16+n)*4];   // uniform
                const float4 wB = *(const float4*)&w_up[(m2b*16+n)*4];   // uniform
                h0[0]+=aa[0]*wA.x; h0[1]+=aa[1]*wA.y; h0[2]+=aa[2]*wA.y; h0[3]+=aa[3]*wA.y;
                h0[4]+=aa[4]*wA.z; h0[5]+=aa[5]*wA.z; h0[6]+=aa[6]*wA.z; h0[7]+=aa[7]*wA.w;
                h1[0]+=aa[0]*wB.x; h1[1]+=aa[1]*wB.y; h1[2]+=aa[2]*wB.y; h1[3]+=aa[3]*wB.y;
                h1[4]+=aa[4]*wB.z; h1[5]+=aa[5]*wB.z; h1[6]+=aa[6]*wB.z; h1[7]+=aa[7]*wB.w;
            }
        }
        #pragma unroll
        for (int qq = 0; qq < 2; ++qq) {
            float* hh = qq ? h1 : h0;
            const int m2 = qq ? m2b : m2a;
            hh[0] += b_up[m2];
            const float inv0 = hh[0];
            const float inv1 = hh[1]*hh[1] + hh[2]*hh[2] + hh[3]*hh[3];
            const float inv2 = hh[4]*hh[4] + hh[5]*hh[5] + hh[6]*hh[6];
            const float inv3 = hh[7]*hh[7];
            const float4 a4 = *(const float4*)&a_act[m2*4];
            const float4 b4 = *(const float4*)&b_act[m2*4];
            const float g0 = sigmoidf_(a4.x*inv0 + b4.x);
            const float g1 = sigmoidf_(a4.y*inv1 + b4.y);
            const float g2 = sigmoidf_(a4.z*inv2 + b4.z);
            const float g3 = sigmoidf_(a4.w*inv3 + b4.w);
            hh[0]*=g0; hh[1]*=g1; hh[2]*=g1; hh[3]*=g1;
            hh[4]*=g2; hh[5]*=g2; hh[6]*=g2; hh[7]*=g3;
        }
        __syncthreads();   // previous chunk's H reads complete before overwrite
        uXR[b*17 + w]     = pkrow(h0);
        uXR[b*17 + 8 + w] = pkrow(h1);
        __syncthreads();   // H visible
        #pragma unroll 1
        for (int s = 0; s < 16; ++s) {
            float hv[8];
            unpkrow(uXR[b*17 + s], hv);
            const float4 wdA = *(const float4*)&w_down[(mA*64 + ch*16 + s)*4];  // uniform
            const float4 wdB = *(const float4*)&w_down[(mB*64 + ch*16 + s)*4];  // uniform
            oaccA[0]+=hv[0]*wdA.x; oaccA[1]+=hv[1]*wdA.y; oaccA[2]+=hv[2]*wdA.y; oaccA[3]+=hv[3]*wdA.y;
            oaccA[4]+=hv[4]*wdA.z; oaccA[5]+=hv[5]*wdA.z; oaccA[6]+=hv[6]*wdA.z; oaccA[7]+=hv[7]*wdA.w;
            oaccB[0]+=hv[0]*wdB.x; oaccB[1]+=hv[1]*wdB.y; oaccB[2]+=hv[2]*wdB.y; oaccB[3]+=hv[3]*wdB.y;
            oaccB[4]+=hv[4]*wdB.z; oaccB[5]+=hv[5]*wdB.z; oaccB[6]+=hv[6]*wdB.z; oaccB[7]+=hv[7]*wdB.w;
        }
    }
    __syncthreads();   // all H reads done: union becomes f32 [64][136] out buffer

    // ---------- epilogue: out = attended + down + b_down (f32), dense coalesced stores ----------
    oaccA[0] += b_down[mA];
    oaccB[0] += b_down[mB];
    *(float4*)&sm[b*136 + mA*8]     = make_float4(attA[0]+oaccA[0], attA[1]+oaccA[1],
                                                  attA[2]+oaccA[2], attA[3]+oaccA[3]);
    *(float4*)&sm[b*136 + mA*8 + 4] = make_float4(attA[4]+oaccA[4], attA[5]+oaccA[5],
                                                  attA[6]+oaccA[6], attA[7]+oaccA[7]);
    *(float4*)&sm[b*136 + mB*8]     = make_float4(attB[0]+oaccB[0], attB[1]+oaccB[1],
                                                  attB[2]+oaccB[2], attB[3]+oaccB[3]);
    *(float4*)&sm[b*136 + mB*8 + 4] = make_float4(attB[4]+oaccB[4], attB[5]+oaccB[5],
                                                  attB[6]+oaccB[6], attB[7]+oaccB[7]);
    __syncthreads();
    {
        float4* og = (float4*)outg + (size_t)g * 2048;
        #pragma unroll
        for (int r = 0; r < 4; ++r) {
            const int idx = r * TPB + t;
            const int el = idx >> 5, off = idx & 31;
            og[idx] = *(const float4*)&sm[el*136 + off*4];
        }
    }
}

extern "C" void kernel_launch(void* const* d_in, const int* in_sizes, int n_in,
                              void* d_out, int out_size, void* d_ws, size_t ws_size,
                              hipStream_t stream) {
    const float* x       = (const float*)d_in[0];
    const float* w_right = (const float*)d_in[1];
    const float* a_norm  = (const float*)d_in[2];
    const float* w_gp    = (const float*)d_in[3];
    const float* w_left  = (const float*)d_in[4];
    const float* b_left  = (const float*)d_in[5];
    const float* w_up    = (const float*)d_in[6];
    const float* b_up    = (const float*)d_in[7];
    const float* a_act   = (const float*)d_in[8];
    const float* b_act   = (const float*)d_in[9];
    const float* w_down  = (const float*)d_in[10];
    const float* b_down  = (const float*)d_in[11];
    float* out = (float*)d_out;

    const int B = in_sizes[0] / 128;        // 65536
    const int nblocks = B / 64;             // 1024

    (void)hipFuncSetAttribute((const void*)mv_block_kernel,
                              hipFuncAttributeMaxDynamicSharedMemorySize, SMEM_BYTES);
    mv_block_kernel<<<nblocks, TPB, SMEM_BYTES, stream>>>(
        x, w_right, a_norm, w_gp, w_left, b_left,
        w_up, b_up, a_act, b_act, w_down, b_down, out);
}